// Round 7
// baseline (353.071 us; speedup 1.0000x reference)
//
#include <hip/hip_runtime.h>

// Chain of 9 Linear layers, no activation => collapse to one affine map.
// dims: 784 -> 69 -> 31 -> 10 -> ... -> 10
//
//   P1 (1 block):   S8 = W8*...*W1 [10,69], beff = S8 @ b0 + collapsed bias
//   P2 (35 blocks): Wt2 padded layout [200 j-quads][11 float4]
//   MAIN: out[b][o] = sum_j x[b][j]*Wt[j][o] + beff[o]
//
// MAIN (R7): R6 + 2 rows per lane to halve weight-LDS instructions.
//   R6 (est 87us) was limited by the weight ds_read_b128 stream: 250/wave,
//   >=8cyc each on the 128B/cyc LDS return path (~27-40us/CU), 10x the x
//   bytes. Now each lane owns a ROW PAIR: same 10 weight reads per jb feed
//   80 FMAs (acc0[10]+acc1[10]) -> weight reads per row halved. x loads stay
//   coalesced (8 consecutive lanes = 1 full 128B line per row). 256-thr
//   blocks, 64 rows, 1024 blocks = 4 blocks/CU (LDS 35.2KB*4=141KB),
//   16 waves/CU. Bank-quad start (3s+o)&7 is a permutation across s ->
//   conflict-free 8-way broadcast. shfl_xor butterfly combine, no atomics.

__global__ void prep_collapse(
    const float* __restrict__ W1, const float* __restrict__ b1,
    const float* __restrict__ W2, const float* __restrict__ b2,
    const float* __restrict__ W3, const float* __restrict__ b3,
    const float* __restrict__ W4, const float* __restrict__ b4,
    const float* __restrict__ W5, const float* __restrict__ b5,
    const float* __restrict__ W6, const float* __restrict__ b6,
    const float* __restrict__ W7, const float* __restrict__ b7,
    const float* __restrict__ W8, const float* __restrict__ b8,
    const float* __restrict__ b0,
    float* __restrict__ S8out, float* __restrict__ beff)
{
    __shared__ float Sa[31 * 69], Sb[31 * 69];
    __shared__ float da[31], db[31];
    const int t = threadIdx.x;
    const int nt = blockDim.x;

    for (int i = t; i < 31 * 69; i += nt) Sa[i] = W1[i];
    for (int i = t; i < 31; i += nt) da[i] = b1[i];
    __syncthreads();

    for (int i = t; i < 10 * 69; i += nt) {
        int o = i / 69, c = i - o * 69;
        float s = 0.f;
        for (int k = 0; k < 31; k++) s += W2[o * 31 + k] * Sa[k * 69 + c];
        Sb[i] = s;
    }
    for (int i = t; i < 10; i += nt) {
        float s = b2[i];
        for (int k = 0; k < 31; k++) s += W2[i * 31 + k] * da[k];
        db[i] = s;
    }
    __syncthreads();

    const float* Wk[6] = { W3, W4, W5, W6, W7, W8 };
    const float* bk[6] = { b3, b4, b5, b6, b7, b8 };
    int src = 1;  // runtime ternaries: gfx950 rejects arrays of LDS pointers
    for (int st = 0; st < 6; st++) {
        const float* W = Wk[st];
        const float* bb = bk[st];
        float* S  = src ? Sb : Sa;
        float* D  = src ? Sa : Sb;
        float* dd = src ? db : da;
        float* dn = src ? da : db;
        for (int i = t; i < 10 * 69; i += nt) {
            int o = i / 69, c = i - o * 69;
            float s = 0.f;
            for (int k = 0; k < 10; k++) s += W[o * 10 + k] * S[k * 69 + c];
            D[i] = s;
        }
        for (int i = t; i < 10; i += nt) {
            float s = bb[i];
            for (int k = 0; k < 10; k++) s += W[i * 10 + k] * dd[k];
            dn[i] = s;
        }
        __syncthreads();
        src ^= 1;
    }

    float* S  = src ? Sb : Sa;
    float* dd = src ? db : da;
    for (int i = t; i < 690; i += nt) S8out[i] = S[i];
    for (int i = t; i < 10; i += nt) {
        float s = dd[i];
        for (int k = 0; k < 69; k++) s += S[i * 69 + k] * b0[k];
        beff[i] = s;
    }
}

// Wt2 layout: [200 j-quads][11 float4]; entry (j4, o<10) = {W[o][j4*4+k]}_{k=0..3}
// (composed weight); o==10 and j4 in [196,200) are zero padding.
__global__ void prep_fold0(const float* __restrict__ W0,
                           const float* __restrict__ S8,
                           float* __restrict__ Wt2)
{
    int idx = blockIdx.x * blockDim.x + threadIdx.x;  // 0..8799
    if (idx >= 8800) return;
    int j4 = idx / 44, rem = idx - j4 * 44;
    float val = 0.f;
    if (rem < 40) {
        int o = rem >> 2, k = rem & 3, j = j4 * 4 + k;
        if (j < 784) {
            for (int u = 0; u < 69; u++) val += S8[o * 69 + u] * W0[u * 784 + j];
        }
    }
    Wt2[idx] = val;
}

// ---- main ----

__global__ __launch_bounds__(256, 4) void linear_main(
    const float* __restrict__ x, const float* __restrict__ Wt2,
    const float* __restrict__ beff, float* __restrict__ out)
{
    __shared__ float4 wlds[2200];   // 35.2 KB
    const int t = threadIdx.x;
    const int s = t & 7;                             // j-segment (8 per row group)
    const long r0 = (long)blockIdx.x * 64 + (t >> 3) * 2;  // row pair
    const float* xr0 = x + r0 * 784;
    const float* xr1 = xr0 + 784;

    // stage weights (independent of the first x loads)
    {
        const float4* wg = (const float4*)Wt2;
        for (int i = t; i < 2200; i += 256) wlds[i] = wg[i];
    }

    float acc0[10], acc1[10];
#pragma unroll
    for (int o = 0; o < 10; o++) { acc0[o] = 0.f; acc1[o] = 0.f; }

    // first x loads issued before the barrier
    float4 xv0 = *(const float4*)(xr0 + s * 4);
    float4 xv1 = *(const float4*)(xr1 + s * 4);
    __syncthreads();

    for (int jb = 0; jb < 25; jb++) {
        float4 xc0 = xv0, xc1 = xv1;
        if (jb < 24) {  // prefetch next chunk; tail cols have zero weights
            int jn = (jb + 1) * 32 + s * 4;
            jn = jn > 780 ? 780 : jn;
            xv0 = *(const float4*)(xr0 + jn);
            xv1 = *(const float4*)(xr1 + jn);
        }
        const float4* wrow = &wlds[(jb * 8 + s) * 11];
#pragma unroll
        for (int o = 0; o < 10; o++) {
            float4 wv = wrow[o];
            acc0[o] = fmaf(xc0.x, wv.x, acc0[o]);
            acc0[o] = fmaf(xc0.y, wv.y, acc0[o]);
            acc0[o] = fmaf(xc0.z, wv.z, acc0[o]);
            acc0[o] = fmaf(xc0.w, wv.w, acc0[o]);
            acc1[o] = fmaf(xc1.x, wv.x, acc1[o]);
            acc1[o] = fmaf(xc1.y, wv.y, acc1[o]);
            acc1[o] = fmaf(xc1.z, wv.z, acc1[o]);
            acc1[o] = fmaf(xc1.w, wv.w, acc1[o]);
        }
    }

    // butterfly sum over the 8 lanes sharing this row pair
#pragma unroll
    for (int m = 1; m < 8; m <<= 1) {
#pragma unroll
        for (int o = 0; o < 10; o++) {
            acc0[o] += __shfl_xor(acc0[o], m, 64);
            acc1[o] += __shfl_xor(acc1[o], m, 64);
        }
    }

    // lanes s<5 write float2 per row (out + row*10 is 8B-aligned)
    if (s < 5) {
        float lo0 = 0.f, hi0 = 0.f, lo1 = 0.f, hi1 = 0.f;
#pragma unroll
        for (int o = 0; o < 5; o++) {
            if (s == o) {
                lo0 = acc0[2 * o]; hi0 = acc0[2 * o + 1];
                lo1 = acc1[2 * o]; hi1 = acc1[2 * o + 1];
            }
        }
        float be0 = beff[s * 2], be1 = beff[s * 2 + 1];
        *(float2*)(out + r0 * 10 + s * 2) = make_float2(lo0 + be0, hi0 + be1);
        *(float2*)(out + (r0 + 1) * 10 + s * 2) = make_float2(lo1 + be0, hi1 + be1);
    }
}

extern "C" void kernel_launch(void* const* d_in, const int* in_sizes, int n_in,
                              void* d_out, int out_size, void* d_ws, size_t ws_size,
                              hipStream_t stream) {
    const float* x  = (const float*)d_in[0];
    const float* W0 = (const float*)d_in[1];
    const float* b0 = (const float*)d_in[2];
    const float* W1 = (const float*)d_in[3];
    const float* b1 = (const float*)d_in[4];
    const float* W2 = (const float*)d_in[5];
    const float* b2 = (const float*)d_in[6];
    const float* W3 = (const float*)d_in[7];
    const float* b3 = (const float*)d_in[8];
    const float* W4 = (const float*)d_in[9];
    const float* b4 = (const float*)d_in[10];
    const float* W5 = (const float*)d_in[11];
    const float* b5 = (const float*)d_in[12];
    const float* W6 = (const float*)d_in[13];
    const float* b6 = (const float*)d_in[14];
    const float* W7 = (const float*)d_in[15];
    const float* b7 = (const float*)d_in[16];
    const float* W8 = (const float*)d_in[17];
    const float* b8 = (const float*)d_in[18];

    float* ws   = (float*)d_ws;
    float* Wt2  = ws;            // 8800 floats: [200 j4][11 float4]
    float* beff = ws + 8800;     // 10 floats
    float* S8   = ws + 8816;     // 690 floats

    float* out = (float*)d_out;
    const int B = in_sizes[0] / 784;  // 65536

    prep_collapse<<<1, 256, 0, stream>>>(W1, b1, W2, b2, W3, b3, W4, b4,
                                         W5, b5, W6, b6, W7, b7, W8, b8,
                                         b0, S8, beff);
    prep_fold0<<<35, 256, 0, stream>>>(W0, S8, Wt2);
    linear_main<<<B / 64, 256, 0, stream>>>(x, Wt2, beff, out);
}